// Round 4
// baseline (327.887 us; speedup 1.0000x reference)
//
#include <hip/hip_runtime.h>

typedef _Float16 h16;
typedef __attribute__((ext_vector_type(4))) _Float16 half4v;
typedef __attribute__((ext_vector_type(8))) _Float16 half8v;
typedef __attribute__((ext_vector_type(4))) float f32x4;

static constexpr int Tn = 256;   // keys/values per head
static constexpr int Dn = 64;    // head dim
static constexpr int Sn = 128;   // query rows per head
static constexpr int KSTR = 72;  // halves; K tile [256][KSTR] (36864 B), reused as V^T chunks
static constexpr int PSTR = 40;  // halves; P chunk [16][PSTR] per wave, single-buffered
static constexpr int VCH  = 64 * KSTR;  // 4608 halves: one V^T chunk [64 d][72 t] == 64 K rows

#define MFMA_F16 __builtin_amdgcn_mfma_f32_16x16x32_f16

// ONE block per (b,w) head, 8 waves x 16 query rows. Per-thread state = R3's
// (acc[16] = 64 regs, ~72 VGPR), but single K/V fetch per head (no R3 duplicate
// traffic) and LDS 47104 B -> 3 blocks/CU x 8 waves = 24 waves/CU (75% occupancy,
// 2.5x R3). R1-vs-R3 showed time is pinned by per-block latency chains with only
// 2-3 resident blocks; this config triples independent-block fillers per CU while
// keeping fetch compulsory.
__global__ __launch_bounds__(512, 6)
void attn_kernel(const float* __restrict__ Q, const float* __restrict__ K,
                 const float* __restrict__ V, float* __restrict__ O)
{
    __shared__ __align__(16) h16 KV[Tn * KSTR];      // 36864 B: K, then V^T (chunk-major)
    __shared__ __align__(16) h16 Pb[8 * 16 * PSTR];  // 10240 B: P round-trip, 1 per wave

    const int head = blockIdx.x;
    const int tid  = threadIdx.x;
    const int wave = tid >> 6;     // 0..7
    const int lane = tid & 63;
    const int quad = lane >> 4;
    const int l16  = lane & 15;

    const float* __restrict__ Kh = K + (size_t)head * (Tn * Dn);
    const float* __restrict__ Vh = V + (size_t)head * (Tn * Dn);
    float* __restrict__ Oh       = O + (size_t)head * (Sn * Dn);

    // ---- Q A-fragments (global fp32 -> fp16 regs). A[m=l16][k=quad*8+j].
    half8v qf[2];
    {
        const float* qrow = Q + (wave * 16 + l16) * Dn;
#pragma unroll
        for (int kt = 0; kt < 2; ++kt) {
            float4 a = *reinterpret_cast<const float4*>(qrow + kt * 32 + quad * 8);
            float4 b = *reinterpret_cast<const float4*>(qrow + kt * 32 + quad * 8 + 4);
            half8v f;
            f[0] = (h16)a.x; f[1] = (h16)a.y; f[2] = (h16)a.z; f[3] = (h16)a.w;
            f[4] = (h16)b.x; f[5] = (h16)b.y; f[6] = (h16)b.z; f[7] = (h16)b.w;
            qf[kt] = f;
        }
    }

    // ---- stage K: coalesced float4 reads, b64 fp16 LDS writes, [t][d] stride KSTR
#pragma unroll
    for (int it = 0; it < 8; ++it) {
        int f   = it * 512 + tid;
        int row = f >> 4;          // t
        int c4  = (f & 15) << 2;   // d
        float4 kv = *reinterpret_cast<const float4*>(Kh + row * Dn + c4);
        half4v hv;
        hv[0] = (h16)kv.x; hv[1] = (h16)kv.y; hv[2] = (h16)kv.z; hv[3] = (h16)kv.w;
        *reinterpret_cast<half4v*>(&KV[row * KSTR + c4]) = hv;
    }
    __syncthreads();   // B1: K staged

    // ---- scores: acc[n] = Qstrip(16xD) @ K^T(Dx256); B[k=d][n=t] contiguous b128
    f32x4 acc[16] = {};
#pragma unroll
    for (int n = 0; n < 16; ++n) {
#pragma unroll
        for (int kt = 0; kt < 2; ++kt) {
            half8v bf = *reinterpret_cast<const half8v*>(
                &KV[(n * 16 + l16) * KSTR + kt * 32 + quad * 8]);
            acc[n] = MFMA_F16(qf[kt], bf, acc[n], 0, 0, 0);
        }
    }

    // ---- mask (p==0 -> -1e5) + softmax. Row = quad*4+r; cols over 16 lanes x 16 tiles.
    float rinv[4];
#pragma unroll
    for (int r = 0; r < 4; ++r) {
        float mx = -3.0e38f;
#pragma unroll
        for (int n = 0; n < 16; ++n) {
            float p = acc[n][r];
            p = (p == 0.0f) ? -100000.0f : p;
            acc[n][r] = p;
            mx = fmaxf(mx, p);
        }
        mx = fmaxf(mx, __shfl_xor(mx, 1));
        mx = fmaxf(mx, __shfl_xor(mx, 2));
        mx = fmaxf(mx, __shfl_xor(mx, 4));
        mx = fmaxf(mx, __shfl_xor(mx, 8));
        float sm = 0.0f;
#pragma unroll
        for (int n = 0; n < 16; ++n) {
            float e = __expf(acc[n][r] - mx);
            acc[n][r] = e;   // unnormalized weight
            sm += e;
        }
        sm += __shfl_xor(sm, 1);
        sm += __shfl_xor(sm, 2);
        sm += __shfl_xor(sm, 4);
        sm += __shfl_xor(sm, 8);
        rinv[r] = 1.0f / sm;
    }

    // ---- all waves done with K; re-stage region as V^T, chunk-major [c][64 d][72 t].
    // Swizzle within chunk: tc = (t&63) ^ (quad<<3), quad == ((d>>2)&3) for written d
    // -> conflict-free scatter writes, contiguous b128 reads in PV.
    __syncthreads();
#pragma unroll
    for (int i = 0; i < 8; ++i) {
        int dbase = (i >> 1) * 16 + quad * 4;              // 0..63, low 4 bits = quad*4
        int t     = ((i & 1) * 8 + wave) * 16 + l16;       // 0..255
        float4 vv = *reinterpret_cast<const float4*>(Vh + t * Dn + dbase);
        int c  = t >> 6;
        int tc = (t & 63) ^ (quad << 3);
        KV[c * VCH + (dbase + 0) * KSTR + tc] = (h16)vv.x;
        KV[c * VCH + (dbase + 1) * KSTR + tc] = (h16)vv.y;
        KV[c * VCH + (dbase + 2) * KSTR + tc] = (h16)vv.z;
        KV[c * VCH + (dbase + 3) * KSTR + tc] = (h16)vv.w;
    }
    __syncthreads();   // V^T staged & visible

    // ---- O = P @ V over 8 chunks of 32 t. P: C-layout regs -> LDS (swizzled) -> A-frag.
    // Single wave-private buffer: same-wave DS ops are ordered, so chunk c's pa read
    // completes before chunk c+1's scatter writes the same bytes.
    f32x4 oacc[4] = {};
    h16* buf = &Pb[wave * 16 * PSTR];
#pragma unroll
    for (int c = 0; c < 8; ++c) {
#pragma unroll
        for (int nn = 0; nn < 2; ++nn) {
            int n = 2 * c + nn;
#pragma unroll
            for (int r = 0; r < 4; ++r) {
                int row = quad * 4 + r;
                int col = (nn * 16 + l16) ^ (quad << 3);  // ((row>>2)&3)==quad
                buf[row * PSTR + col] = (h16)acc[n][r];
            }
        }
        asm volatile("s_waitcnt lgkmcnt(0)" ::: "memory");  // LDS write->read hazard (wave-private)
        half8v pa = *reinterpret_cast<const half8v*>(
            &buf[l16 * PSTR + ((quad ^ (l16 >> 2)) << 3)]);
#pragma unroll
        for (int dt = 0; dt < 4; ++dt) {
            half8v vb = *reinterpret_cast<const half8v*>(
                &KV[(c >> 1) * VCH + (dt * 16 + l16) * KSTR + (c & 1) * 32 +
                    ((quad ^ (l16 >> 2)) << 3)]);
            oacc[dt] = MFMA_F16(pa, vb, oacc[dt], 0, 0, 0);
        }
    }

    // ---- epilogue: scale by 1/rowsum, dword stores (16 lanes x 64B segments)
#pragma unroll
    for (int dt = 0; dt < 4; ++dt)
#pragma unroll
        for (int r = 0; r < 4; ++r) {
            int s = wave * 16 + quad * 4 + r;
            Oh[s * Dn + dt * 16 + l16] = oacc[dt][r] * rinv[r];
        }
}

extern "C" void kernel_launch(void* const* d_in, const int* in_sizes, int n_in,
                              void* d_out, int out_size, void* d_ws, size_t ws_size,
                              hipStream_t stream) {
    (void)n_in; (void)out_size; (void)d_ws; (void)ws_size;
    const float* q = (const float*)d_in[0];
    const float* k = (const float*)d_in[1];
    const float* v = (const float*)d_in[2];
    float* o = (float*)d_out;
    const int heads = in_sizes[1] / (Tn * Dn);   // B*W = 2048
    attn_kernel<<<dim3(heads), dim3(512), 0, stream>>>(q, k, v, o);
}

// Round 5
// 303.541 us; speedup vs baseline: 1.0802x; 1.0802x over previous
//
#include <hip/hip_runtime.h>

typedef _Float16 h16;
typedef __attribute__((ext_vector_type(4))) _Float16 half4v;
typedef __attribute__((ext_vector_type(8))) _Float16 half8v;
typedef __attribute__((ext_vector_type(4))) float f32x4;

static constexpr int Tn = 256;   // keys/values per head
static constexpr int Dn = 64;    // head dim
static constexpr int Sn = 128;   // query rows per head
static constexpr int KSTR = 72;  // halves; K tile [256][KSTR] (36864 B), reused as V^T chunks
static constexpr int PSTR = 40;  // halves; P chunk [16][PSTR] per wave, single-buffered
static constexpr int VCH  = 64 * KSTR;  // 4608 halves: one V^T chunk [64 d][72 t] == 64 K rows

#define MFMA_F16 __builtin_amdgcn_mfma_f32_16x16x32_f16

// PERSISTENT: grid = 1 block/CU (256 blocks, 8 waves x 16 query rows), each block
// loops over ~8 heads with a double-buffered K tile. Cross-head pipeline:
//   - V[h] streams during QK[h] (chunk loads drained at segment barriers, scattered
//     into dead K rows of buf[cur] — R0's verified aliasing scheme)
//   - K[h+1] streams during PV[h] (barrier-free region: P round-trip is wave-private
//     lgkmcnt only), two 16-reg batches -> cvt -> buf[cur^1]
//   - Q fragments loaded ONCE (query shared across heads)
// R1/R3/R4 showed occupancy (21->57%) does not move time: phase-locked blocks leave
// HBM idle during compute phases. This keeps the memory pipe continuously busy
// inside one block instead. launch_bounds(512,2) = 256 regs/thread: no spill
// (R2/R4 lesson: acc[16]=64 AGPRs + working set needs ~130; caps below that spill).
__global__ __launch_bounds__(512, 2)
void attn_kernel(const float* __restrict__ Q, const float* __restrict__ K,
                 const float* __restrict__ V, float* __restrict__ O, int nheads)
{
    __shared__ __align__(16) h16 KV[2][Tn * KSTR];   // 73728 B: K / V^T, double-buffered
    __shared__ __align__(16) h16 Pb[8 * 16 * PSTR];  // 10240 B: P round-trip, 1 per wave

    const int tid  = threadIdx.x;
    const int wave = tid >> 6;     // 0..7
    const int lane = tid & 63;
    const int quad = lane >> 4;
    const int l16  = lane & 15;

    // ---- Q A-fragments, loaded ONCE (same query for every head). A[m=l16][k=quad*8+j].
    half8v qf[2];
    {
        const float* qrow = Q + (wave * 16 + l16) * Dn;
#pragma unroll
        for (int kt = 0; kt < 2; ++kt) {
            float4 a = *reinterpret_cast<const float4*>(qrow + kt * 32 + quad * 8);
            float4 b = *reinterpret_cast<const float4*>(qrow + kt * 32 + quad * 8 + 4);
            half8v f;
            f[0] = (h16)a.x; f[1] = (h16)a.y; f[2] = (h16)a.z; f[3] = (h16)a.w;
            f[4] = (h16)b.x; f[5] = (h16)b.y; f[6] = (h16)b.z; f[7] = (h16)b.w;
            qf[kt] = f;
        }
    }

    // ---- prologue: stage K[first head] into buf 0 (coalesced float4, fp16 [t][d])
    if ((int)blockIdx.x < nheads) {
        const float* Kh = K + (size_t)blockIdx.x * (Tn * Dn);
#pragma unroll
        for (int it = 0; it < 8; ++it) {
            int f   = it * 512 + tid;
            int row = f >> 4;          // t
            int c4  = (f & 15) << 2;   // d
            float4 kv = *reinterpret_cast<const float4*>(Kh + row * Dn + c4);
            half4v hv;
            hv[0] = (h16)kv.x; hv[1] = (h16)kv.y; hv[2] = (h16)kv.z; hv[3] = (h16)kv.w;
            *reinterpret_cast<half4v*>(&KV[0][row * KSTR + c4]) = hv;
        }
    }
    __syncthreads();

    int cur = 0;
    for (int head = blockIdx.x; head < nheads; head += gridDim.x) {
        const float* __restrict__ Vh = V + (size_t)head * (Tn * Dn);
        float* __restrict__ Oh       = O + (size_t)head * (Sn * Dn);
        h16* KB = KV[cur];

        f32x4 acc[16] = {};
        float4 vreg[4];   // in-flight V chunk: V[t = c*128 + wave*16 + l16][j*16+quad*4 ..+3]

        // issue V chunk 0 loads (t in [0,128)) — stream under QK segment 0
#pragma unroll
        for (int j = 0; j < 4; ++j)
            vreg[j] = *reinterpret_cast<const float4*>(
                Vh + (wave * 16 + l16) * Dn + j * 16 + quad * 4);

        // ---- QK segment 0: n-tiles 0..7 consume K rows [0,128)
#pragma unroll
        for (int n = 0; n < 8; ++n)
#pragma unroll
            for (int kt = 0; kt < 2; ++kt) {
                half8v bf = *reinterpret_cast<const half8v*>(
                    &KB[(n * 16 + l16) * KSTR + kt * 32 + quad * 8]);
                acc[n] = MFMA_F16(qf[kt], bf, acc[n], 0, 0, 0);
            }
        __syncthreads();   // all waves done with K rows [0,128); chunk-0 loads drained

        // scatter V chunk 0 over dead K rows (swizzle: tc = (t&63)^(quad<<3))
#pragma unroll
        for (int j = 0; j < 4; ++j) {
            int dbase = j * 16 + quad * 4;
            int t     = wave * 16 + l16;        // [0,128)
            int c64   = t >> 6;
            int tc    = (t & 63) ^ (quad << 3);
            float4 vv = vreg[j];
            KB[c64 * VCH + (dbase + 0) * KSTR + tc] = (h16)vv.x;
            KB[c64 * VCH + (dbase + 1) * KSTR + tc] = (h16)vv.y;
            KB[c64 * VCH + (dbase + 2) * KSTR + tc] = (h16)vv.z;
            KB[c64 * VCH + (dbase + 3) * KSTR + tc] = (h16)vv.w;
        }

        // issue V chunk 1 loads (t in [128,256)) — stream under QK segment 1
#pragma unroll
        for (int j = 0; j < 4; ++j)
            vreg[j] = *reinterpret_cast<const float4*>(
                Vh + (128 + wave * 16 + l16) * Dn + j * 16 + quad * 4);

        // ---- QK segment 1: n-tiles 8..15 consume K rows [128,256)
#pragma unroll
        for (int n = 8; n < 16; ++n)
#pragma unroll
            for (int kt = 0; kt < 2; ++kt) {
                half8v bf = *reinterpret_cast<const half8v*>(
                    &KB[(n * 16 + l16) * KSTR + kt * 32 + quad * 8]);
                acc[n] = MFMA_F16(qf[kt], bf, acc[n], 0, 0, 0);
            }
        __syncthreads();   // K rows [128,256) dead; chunk-1 loads drained

        // scatter V chunk 1
#pragma unroll
        for (int j = 0; j < 4; ++j) {
            int dbase = j * 16 + quad * 4;
            int t     = 128 + wave * 16 + l16;  // [128,256)
            int c64   = t >> 6;
            int tc    = (t & 63) ^ (quad << 3);
            float4 vv = vreg[j];
            KB[c64 * VCH + (dbase + 0) * KSTR + tc] = (h16)vv.x;
            KB[c64 * VCH + (dbase + 1) * KSTR + tc] = (h16)vv.y;
            KB[c64 * VCH + (dbase + 2) * KSTR + tc] = (h16)vv.z;
            KB[c64 * VCH + (dbase + 3) * KSTR + tc] = (h16)vv.w;
        }

        // ---- mask (p==0 -> -1e5) + softmax (covers scatter's lgkm drain)
        float rinv[4];
#pragma unroll
        for (int r = 0; r < 4; ++r) {
            float mx = -3.0e38f;
#pragma unroll
            for (int n = 0; n < 16; ++n) {
                float p = acc[n][r];
                p = (p == 0.0f) ? -100000.0f : p;
                acc[n][r] = p;
                mx = fmaxf(mx, p);
            }
            mx = fmaxf(mx, __shfl_xor(mx, 1));
            mx = fmaxf(mx, __shfl_xor(mx, 2));
            mx = fmaxf(mx, __shfl_xor(mx, 4));
            mx = fmaxf(mx, __shfl_xor(mx, 8));
            float sm = 0.0f;
#pragma unroll
            for (int n = 0; n < 16; ++n) {
                float e = __expf(acc[n][r] - mx);
                acc[n][r] = e;   // unnormalized weight
                sm += e;
            }
            sm += __shfl_xor(sm, 1);
            sm += __shfl_xor(sm, 2);
            sm += __shfl_xor(sm, 4);
            sm += __shfl_xor(sm, 8);
            rinv[r] = 1.0f / sm;
        }
        __syncthreads();   // V^T fully staged & visible

        // ---- PV (barrier-free region) + K[h+1] prefetch streaming underneath.
        const int  hn = head + gridDim.x;
        const bool pf = hn < nheads;
        const float* __restrict__ Kn = K + (size_t)hn * (Tn * Dn);
        h16* KBn = KV[cur ^ 1];
        float4 kreg[4];
        if (pf) {
#pragma unroll
            for (int it = 0; it < 4; ++it) {           // batch 0: K rows [0,128)
                int f = it * 512 + tid;
                kreg[it] = *reinterpret_cast<const float4*>(Kn + (f >> 4) * Dn + ((f & 15) << 2));
            }
        }

        f32x4 oacc[4] = {};
        h16* buf = &Pb[wave * 16 * PSTR];
#pragma unroll
        for (int c = 0; c < 8; ++c) {
#pragma unroll
            for (int nn = 0; nn < 2; ++nn) {
                int n = 2 * c + nn;
#pragma unroll
                for (int r = 0; r < 4; ++r) {
                    int row = quad * 4 + r;
                    int col = (nn * 16 + l16) ^ (quad << 3);  // ((row>>2)&3)==quad
                    buf[row * PSTR + col] = (h16)acc[n][r];
                }
            }
            asm volatile("s_waitcnt lgkmcnt(0)" ::: "memory");  // wave-private write->read
            half8v pa = *reinterpret_cast<const half8v*>(
                &buf[l16 * PSTR + ((quad ^ (l16 >> 2)) << 3)]);
#pragma unroll
            for (int dt = 0; dt < 4; ++dt) {
                half8v vb = *reinterpret_cast<const half8v*>(
                    &KB[(c >> 1) * VCH + (dt * 16 + l16) * KSTR + (c & 1) * 32 +
                        ((quad ^ (l16 >> 2)) << 3)]);
                oacc[dt] = MFMA_F16(pa, vb, oacc[dt], 0, 0, 0);
            }
            if (c == 3 && pf) {
                // write K batch 0 into buf[cur^1]; issue batch 1 (rows [128,256))
#pragma unroll
                for (int it = 0; it < 4; ++it) {
                    int f   = it * 512 + tid;
                    int row = f >> 4;
                    int c4  = (f & 15) << 2;
                    float4 kv = kreg[it];
                    half4v hv;
                    hv[0] = (h16)kv.x; hv[1] = (h16)kv.y; hv[2] = (h16)kv.z; hv[3] = (h16)kv.w;
                    *reinterpret_cast<half4v*>(&KBn[row * KSTR + c4]) = hv;
                }
#pragma unroll
                for (int it = 0; it < 4; ++it) {
                    int f = 2048 + it * 512 + tid;
                    kreg[it] = *reinterpret_cast<const float4*>(Kn + (f >> 4) * Dn + ((f & 15) << 2));
                }
            }
        }
        if (pf) {
#pragma unroll
            for (int it = 0; it < 4; ++it) {           // write K batch 1
                int f   = 2048 + it * 512 + tid;
                int row = f >> 4;
                int c4  = (f & 15) << 2;
                float4 kv = kreg[it];
                half4v hv;
                hv[0] = (h16)kv.x; hv[1] = (h16)kv.y; hv[2] = (h16)kv.z; hv[3] = (h16)kv.w;
                *reinterpret_cast<half4v*>(&KBn[row * KSTR + c4]) = hv;
            }
        }

        // ---- epilogue: scale by 1/rowsum; stores drain under next head's QK
#pragma unroll
        for (int dt = 0; dt < 4; ++dt)
#pragma unroll
            for (int r = 0; r < 4; ++r) {
                int s = wave * 16 + quad * 4 + r;
                Oh[s * Dn + dt * 16 + l16] = oacc[dt][r] * rinv[r];
            }

        __syncthreads();   // K[h+1] staged & visible; buf[cur] PV reads complete
        cur ^= 1;
    }
}

extern "C" void kernel_launch(void* const* d_in, const int* in_sizes, int n_in,
                              void* d_out, int out_size, void* d_ws, size_t ws_size,
                              hipStream_t stream) {
    (void)n_in; (void)out_size; (void)d_ws; (void)ws_size;
    const float* q = (const float*)d_in[0];
    const float* k = (const float*)d_in[1];
    const float* v = (const float*)d_in[2];
    float* o = (float*)d_out;
    const int heads = in_sizes[1] / (Tn * Dn);   // B*W = 2048

    static int ncu = 0;
    if (ncu == 0) {
        hipDeviceProp_t prop;
        ncu = (hipGetDeviceProperties(&prop, 0) == hipSuccess && prop.multiProcessorCount > 0)
                  ? prop.multiProcessorCount : 256;
    }
    int grid = heads < ncu ? heads : ncu;        // 1 persistent block per CU
    attn_kernel<<<dim3(grid), dim3(512), 0, stream>>>(q, k, v, o, heads);
}